// Round 9
// baseline (255.526 us; speedup 1.0000x reference)
//
#include <hip/hip_runtime.h>

typedef _Float16 f16x8 __attribute__((ext_vector_type(8)));
typedef _Float16 f16x4 __attribute__((ext_vector_type(4)));
typedef __fp16   fp16x2 __attribute__((ext_vector_type(2)));
typedef float    f32x4 __attribute__((ext_vector_type(4)));
typedef unsigned int u32x2 __attribute__((ext_vector_type(2)));

__device__ __forceinline__ f32x4 mfma32(f16x8 a, f16x8 b, f32x4 c) {
  return __builtin_amdgcn_mfma_f32_16x16x32_f16(a, b, c, 0, 0, 0);
}
__device__ __forceinline__ f32x4 mfma16(f16x4 a, f16x4 b, f32x4 c) {
#if __has_builtin(__builtin_amdgcn_mfma_f32_16x16x16f16)
  return __builtin_amdgcn_mfma_f32_16x16x16f16(a, b, c, 0, 0, 0);
#else
  f32x4 d;
  asm volatile("v_mfma_f32_16x16x16_f16 %0, %1, %2, %3"
               : "=v"(d) : "v"(a), "v"(b), "v"(c));
  return d;
#endif
}

__device__ __forceinline__ unsigned pk2(float a, float b) {
  union { fp16x2 h; unsigned u; } cv;
  cv.h = __builtin_amdgcn_cvt_pkrtz(a, b);
  return cv.u;
}

// hardware transpose read: per-lane vaddr (32-bit LDS byte offset) = base + 8*lane;
// delivers, for lane l, elems j=0..3 = lds_elem[(l&15) + 16*j + 64*(l>>4)] rel. to base
#define TR_READ(dst, addr, OFF) \
  asm volatile("ds_read_b64_tr_b16 %0, %1 offset:" OFF \
               : "=v"(dst) : "v"(addr) : "memory")

// ---- pre-convert weights to fp16 in workspace (L2-resident reuse) ----
__global__ void cvt_weights(const float* __restrict__ qw, const float* __restrict__ cw,
                            _Float16* __restrict__ wq, _Float16* __restrict__ wc) {
  const int i = blockIdx.x * 256 + threadIdx.x;
  if (i < 384 * 128) wq[i] = (_Float16)qw[i];
  if (i < 128 * 128) wc[i] = (_Float16)cw[i];
}

// One 4x4x4 window per block. 4 waves; wave wv owns heads {2wv, 2wv+1}.
// Lessons: R6/R7 — rolled head loop forces scratch (conditional defs across
// rolled iterations defeat regalloc) -> hp fully unrolled, all indices
// compile-time. R8 — (256,2) lets the compiler take ~176+ total regs
// (VGPR+AGPR unified) -> 2 blocks/CU only. (256,4) caps total at 128/wave:
// unrolled pipeline's true live state ~90-110 fits -> 4 blocks/CU, no spill.
// LDS (32KB):
//   xsm: x-window / o buffer [64 t][128 ch] f16, byte = t*256 + (2*ch ^ ((t&15)<<4))
//   wsm[wv] (4KB/wave): QK phase: k [0,2048) as [si][16ch][16tok], q [2048,4096);
//                       PV phase: P chunk [64 t][32 s], byte = t*64 + (soff ^ ((t&3)<<4))
__global__ void __launch_bounds__(256, 4)
win_attn(const float* __restrict__ xg, const _Float16* __restrict__ wq,
         const float* __restrict__ qbias, const _Float16* __restrict__ wc,
         const float* __restrict__ cb, float* __restrict__ outg)
{
  __shared__ char xsm[16384];
  __shared__ char wsm[4][4096];

  const int tid  = threadIdx.x;
  const int lane = tid & 63;
  const int wv   = tid >> 6;
  const int l15  = lane & 15;
  const int g    = lane >> 4;

  // XCD-bijective swizzle (4096 % 8 == 0): contiguous ww-ranges per XCD
  const int raw = blockIdx.x;
  const int wid = ((raw & 7) << 9) | (raw >> 3);
  const int ww = wid & 15, hh = (wid >> 4) & 15, dd = (wid >> 8) & 7, bb = wid >> 11;

  const f32x4 fz = {0.f, 0.f, 0.f, 0.f};

  // ---------------- stage x window -> xsm (fp16, swizzled token-major) ----------------
  {
    const int m4 = lane & 3, q4 = lane >> 2;
    const int i0 = q4 >> 2, i1 = q4 & 3;
    const int z = dd * 4 + i0, y = hh * 4 + i1;
    const bool yv   = (y < 62);
    const bool full = (ww < 15);
    float va[8][4];
#pragma unroll
    for (int it = 0; it < 8; ++it) {           // issue all global loads first
      const int c = wv * 32 + it * 4 + m4;
      const float* src = xg + (((size_t)(bb * 128 + c) * 32 + (size_t)z) * 3844
                               + (size_t)(y * 62 + ww * 4));
      float a0 = 0.f, a1 = 0.f, a2 = 0.f, a3 = 0.f;
      if (yv) {
        const float2 lo = *reinterpret_cast<const float2*>(src);
        a0 = lo.x; a1 = lo.y;
        if (full) {
          const float2 hi = *reinterpret_cast<const float2*>(src + 2);
          a2 = hi.x; a3 = hi.y;
        }
      }
      va[it][0] = a0; va[it][1] = a1; va[it][2] = a2; va[it][3] = a3;
    }
#pragma unroll
    for (int it = 0; it < 8; ++it) {           // 4x4 lane-quad transpose, packed b64 write
      float v0 = va[it][0], v1 = va[it][1], v2 = va[it][2], v3 = va[it][3];
      float t0 = __shfl_xor((m4 & 1) ? v0 : v1, 1);
      float t1 = __shfl_xor((m4 & 1) ? v2 : v3, 1);
      if (m4 & 1) { v0 = t0; v2 = t1; } else { v1 = t0; v3 = t1; }
      float t2 = __shfl_xor((m4 & 2) ? v0 : v2, 2);
      float t3 = __shfl_xor((m4 & 2) ? v1 : v3, 2);
      if (m4 & 2) { v0 = t2; v1 = t3; } else { v2 = t2; v3 = t3; }
      f16x4 pk; pk[0] = (_Float16)v0; pk[1] = (_Float16)v1;
                pk[2] = (_Float16)v2; pk[3] = (_Float16)v3;
      const int c0 = wv * 32 + it * 4;         // lane holds xs[t=lane][c0..c0+3]
      *reinterpret_cast<f16x4*>(xsm + ((lane * 256 + 2 * c0) ^ ((lane & 15) << 4))) = pk;
    }
  }
  __syncthreads();

  // ---------------- per-head pipeline: QKV GEMM -> attention ----------------
  char* sb = wsm[wv];
  const unsigned sb32 = (unsigned)(unsigned long long)sb;   // LDS byte offset
  const unsigned trb  = sb32 + 8u * (unsigned)lane;

  unsigned long long pm = 0ull;                     // pad flag per token
  if (hh == 15) pm |= 0xFF00FF00FF00FF00ull;        // i1 >= 2
  if (ww == 15) pm |= 0xCCCCCCCCCCCCCCCCull;        // i2 >= 2

  const float LOG2E = 1.4426950408889634f;
  const int swzA = l15 << 4;

  unsigned opk0[4][2], opk1[4][2];                  // packed o per head

#pragma unroll
  for (int hp = 0; hp < 2; ++hp) {
    __builtin_amdgcn_sched_barrier(0);              // keep the two heads' code apart
    // ---- QKV GEMM for head h = 2wv+hp: co 0=q, 1=k, 2=v ----
    f32x4 acc[4][3];
#pragma unroll
    for (int i = 0; i < 4; ++i)
#pragma unroll
      for (int j = 0; j < 3; ++j) acc[i][j] = fz;

#pragma unroll
    for (int kk = 0; kk < 4; ++kk) {
      f16x8 a[4];
#pragma unroll
      for (int ri = 0; ri < 4; ++ri)
        a[ri] = *reinterpret_cast<const f16x8*>(
            xsm + (ri * 16 + l15) * 256 + ((kk * 64 + g * 16) ^ swzA));
#pragma unroll
      for (int co = 0; co < 3; ++co) {
        const int col = co * 128 + wv * 32 + hp * 16 + l15;
        const f16x8 bfr = *reinterpret_cast<const f16x8*>(wq + col * 128 + kk * 32 + g * 8);
#pragma unroll
        for (int ri = 0; ri < 4; ++ri) acc[ri][co] = mfma32(a[ri], bfr, acc[ri][co]);
      }
    }
    // bias; fold softmax scale (hd^-0.5 = 0.25) into q
#pragma unroll
    for (int co = 0; co < 3; ++co) {
      const int col = co * 128 + wv * 32 + hp * 16 + l15;
      const float bias = qbias[col];
      const float sc = (co == 0) ? 0.25f : 1.0f;
#pragma unroll
      for (int ri = 0; ri < 4; ++ri)
#pragma unroll
        for (int r = 0; r < 4; ++r) acc[ri][co][r] = (acc[ri][co][r] + bias) * sc;
    }
    // pack v: vp[ri][p] = f16x2 of v[t = ri*16+g*4+{2p,2p+1}][c = l15]
    unsigned vp[4][2];
#pragma unroll
    for (int ri = 0; ri < 4; ++ri) {
      vp[ri][0] = pk2(acc[ri][2][0], acc[ri][2][1]);
      vp[ri][1] = pk2(acc[ri][2][2], acc[ri][2][3]);
    }

    // ---- write q,k packed: element off = si*256 + ch*16 + (tok&15) ----
#pragma unroll
    for (int ri = 0; ri < 4; ++ri) {
      const int off = ri * 512 + l15 * 32 + g * 8;  // bytes
      u32x2 kw, qw2;
      kw[0]  = pk2(acc[ri][1][0], acc[ri][1][1]);
      kw[1]  = pk2(acc[ri][1][2], acc[ri][1][3]);
      qw2[0] = pk2(acc[ri][0][0], acc[ri][0][1]);
      qw2[1] = pk2(acc[ri][0][2], acc[ri][0][3]);
      *reinterpret_cast<u32x2*>(sb + off)        = kw;
      *reinterpret_cast<u32x2*>(sb + 2048 + off) = qw2;
    }
    asm volatile("s_waitcnt lgkmcnt(0)" ::: "memory");

    // ---- tr reads: ka[si] = k[s=si*16+l15][ch=g*4+j], qa[tj] = q[t=tj*16+l15][ch=g*4+j]
    f16x4 ka[4], qa[4];
    TR_READ(ka[0], trb, "0");
    TR_READ(ka[1], trb, "512");
    TR_READ(ka[2], trb, "1024");
    TR_READ(ka[3], trb, "1536");
    TR_READ(qa[0], trb, "2048");
    TR_READ(qa[1], trb, "2560");
    TR_READ(qa[2], trb, "3072");
    TR_READ(qa[3], trb, "3584");
    asm volatile("s_waitcnt lgkmcnt(0)" ::: "memory");
    __builtin_amdgcn_sched_barrier(0);

    // ---- S^T tiles: st[si][tj] -> s = si*16+g*4+r, t = tj*16+l15 ----
    f32x4 st[4][4];
#pragma unroll
    for (int si = 0; si < 4; ++si)
#pragma unroll
      for (int tj = 0; tj < 4; ++tj) st[si][tj] = mfma16(ka[si], qa[tj], fz);

    // pad mask: -1000 where pad(s) != pad(t)
    if (pm) {
#pragma unroll
      for (int tj = 0; tj < 4; ++tj) {
        const int t = tj * 16 + l15;
        const unsigned ft = (unsigned)(pm >> t) & 1u;
#pragma unroll
        for (int si = 0; si < 4; ++si)
#pragma unroll
          for (int r = 0; r < 4; ++r) {
            const int s = si * 16 + g * 4 + r;
            const unsigned fs = (unsigned)(pm >> s) & 1u;
            if (fs != ft) st[si][tj][r] -= 1000.f;
          }
      }
    }

    // softmax over s: 16 lane-local values per tj + 2 shfl (g groups)
#pragma unroll
    for (int tj = 0; tj < 4; ++tj) {
      float mx = st[0][tj][0];
#pragma unroll
      for (int si = 0; si < 4; ++si)
#pragma unroll
        for (int r = 0; r < 4; ++r) mx = fmaxf(mx, st[si][tj][r]);
      mx = fmaxf(mx, __shfl_xor(mx, 16));
      mx = fmaxf(mx, __shfl_xor(mx, 32));
      float sum = 0.f;
#pragma unroll
      for (int si = 0; si < 4; ++si)
#pragma unroll
        for (int r = 0; r < 4; ++r) {
          const float e = __builtin_amdgcn_exp2f((st[si][tj][r] - mx) * LOG2E);
          st[si][tj][r] = e; sum += e;
        }
      sum += __shfl_xor(sum, 16);
      sum += __shfl_xor(sum, 32);
      const float inv = __builtin_amdgcn_rcpf(sum);
#pragma unroll
      for (int si = 0; si < 4; ++si)
#pragma unroll
        for (int r = 0; r < 4; ++r) st[si][tj][r] *= inv;
    }

    // ---- PV as o^T = v^T @ P^T, chunked over s (kc = 0,1) ----
    f32x4 oat[4] = {fz, fz, fz, fz};
#pragma unroll
    for (int kc = 0; kc < 2; ++kc) {
      // write P chunk [64 t][32 s]: s_local = (ri&1)*16 + g*4 + r
#pragma unroll
      for (int half = 0; half < 2; ++half) {
        const int ri = 2 * kc + half;
#pragma unroll
        for (int tj = 0; tj < 4; ++tj) {
          const int t = tj * 16 + l15;
          u32x2 w;
          w[0] = pk2(st[ri][tj][0], st[ri][tj][1]);
          w[1] = pk2(st[ri][tj][2], st[ri][tj][3]);
          *reinterpret_cast<u32x2*>(sb + t * 64 + ((half * 32 + g * 8) ^ ((t & 3) << 4))) = w;
        }
      }
      // av = v[s = kc*32 + g*8 + e][c = l15] via 4-lane g-group redistribution
      const int srcA = l15 + 32 * (g & 1);
      const unsigned a0 = __shfl(vp[2 * kc][0], srcA);
      const unsigned a1 = __shfl(vp[2 * kc][1], srcA);
      const unsigned a2 = __shfl(vp[2 * kc][0], srcA + 16);
      const unsigned a3 = __shfl(vp[2 * kc][1], srcA + 16);
      const unsigned b0 = __shfl(vp[2 * kc + 1][0], srcA);
      const unsigned b1 = __shfl(vp[2 * kc + 1][1], srcA);
      const unsigned b2 = __shfl(vp[2 * kc + 1][0], srcA + 16);
      const unsigned b3 = __shfl(vp[2 * kc + 1][1], srcA + 16);
      union { unsigned w[4]; f16x8 v; } av;
      const bool hi = (g >= 2);
      av.w[0] = hi ? b0 : a0; av.w[1] = hi ? b1 : a1;
      av.w[2] = hi ? b2 : a2; av.w[3] = hi ? b3 : a3;
      asm volatile("s_waitcnt lgkmcnt(0)" ::: "memory");
      // pa[tj] = P[t = tj*16 + l15][s_local = g*8 + e]; mfma(av, pa) -> D[c][t]
#pragma unroll
      for (int tj = 0; tj < 4; ++tj) {
        const int t = tj * 16 + l15;
        const f16x8 pa = *reinterpret_cast<const f16x8*>(
            sb + t * 64 + ((g * 16) ^ ((t & 3) << 4)));
        oat[tj] = mfma32(av.v, pa, oat[tj]);
      }
    }

    // pack o: lane holds o[t = tj*16+l15][c = h*16 + g*4 + {0..3}]
    if (hp == 0) {
#pragma unroll
      for (int tj = 0; tj < 4; ++tj) {
        opk0[tj][0] = pk2(oat[tj][0], oat[tj][1]);
        opk0[tj][1] = pk2(oat[tj][2], oat[tj][3]);
      }
    } else {
#pragma unroll
      for (int tj = 0; tj < 4; ++tj) {
        opk1[tj][0] = pk2(oat[tj][0], oat[tj][1]);
        opk1[tj][1] = pk2(oat[tj][2], oat[tj][3]);
      }
    }
  }
  __syncthreads();   // all waves done reading x from xsm -> becomes o buffer

  // ---- write o (both heads) to xsm ----
#pragma unroll
  for (int tj = 0; tj < 4; ++tj) {
    const int t = tj * 16 + l15;
    u32x2 w0; w0[0] = opk0[tj][0]; w0[1] = opk0[tj][1];
    *reinterpret_cast<u32x2*>(xsm + t * 256 + (((2 * wv) * 32 + g * 8) ^ ((t & 15) << 4))) = w0;
    u32x2 w1; w1[0] = opk1[tj][0]; w1[1] = opk1[tj][1];
    *reinterpret_cast<u32x2*>(xsm + t * 256 + (((2 * wv + 1) * 32 + g * 8) ^ ((t & 15) << 4))) = w1;
  }
  __syncthreads();

  // ---------------- 1x1x1 conv GEMM + store ----------------
  f32x4 cacc[4][2];
#pragma unroll
  for (int i = 0; i < 4; ++i) { cacc[i][0] = fz; cacc[i][1] = fz; }
#pragma unroll
  for (int kk = 0; kk < 4; ++kk) {
    f16x8 a[4];
#pragma unroll
    for (int ri = 0; ri < 4; ++ri)
      a[ri] = *reinterpret_cast<const f16x8*>(
          xsm + (ri * 16 + l15) * 256 + ((kk * 64 + g * 16) ^ swzA));
#pragma unroll
    for (int co = 0; co < 2; ++co) {
      const int cout = wv * 32 + co * 16 + l15;
      const f16x8 bfr = *reinterpret_cast<const f16x8*>(wc + cout * 128 + kk * 32 + g * 8);
#pragma unroll
      for (int ri = 0; ri < 4; ++ri) cacc[ri][co] = mfma32(a[ri], bfr, cacc[ri][co]);
    }
  }
  // rows: t = ri*16 + g*4 + r -> i0 = ri (z), i1 = g (y), i2 = r (x)
  const int y = hh * 4 + g;
  if (y < 62) {
#pragma unroll
    for (int co = 0; co < 2; ++co) {
      const int cout = wv * 32 + co * 16 + l15;
      const float bias = cb[cout];
#pragma unroll
      for (int ri = 0; ri < 4; ++ri) {
        const int z = dd * 4 + ri;
        float* dst = outg + (((size_t)(bb * 128 + cout) * 32 + (size_t)z) * 3844
                             + (size_t)(y * 62 + ww * 4));
        float2 lo; lo.x = cacc[ri][co][0] + bias; lo.y = cacc[ri][co][1] + bias;
        *reinterpret_cast<float2*>(dst) = lo;
        if (ww < 15) {
          float2 hi; hi.x = cacc[ri][co][2] + bias; hi.y = cacc[ri][co][3] + bias;
          *reinterpret_cast<float2*>(dst + 2) = hi;
        }
      }
    }
  }
}

extern "C" void kernel_launch(void* const* d_in, const int* in_sizes, int n_in,
                              void* d_out, int out_size, void* d_ws, size_t ws_size,
                              hipStream_t stream) {
  const float* x  = (const float*)d_in[0];
  const float* qw = (const float*)d_in[1];
  const float* qb = (const float*)d_in[2];
  const float* cw = (const float*)d_in[3];
  const float* cb = (const float*)d_in[4];
  float* out = (float*)d_out;

  if (ws_size < (size_t)(384 * 128 + 128 * 128) * sizeof(_Float16)) return;
  _Float16* wq = (_Float16*)d_ws;
  _Float16* wc = wq + 384 * 128;

  cvt_weights<<<192, 256, 0, stream>>>(qw, cw, wq, wc);
  win_attn<<<4096, 256, 0, stream>>>(x, wq, qb, wc, cb, out);
}

// Round 10
// 190.119 us; speedup vs baseline: 1.3440x; 1.3440x over previous
//
#include <hip/hip_runtime.h>

typedef _Float16 f16x8 __attribute__((ext_vector_type(8)));
typedef _Float16 f16x4 __attribute__((ext_vector_type(4)));
typedef __fp16   fp16x2 __attribute__((ext_vector_type(2)));
typedef float    f32x4 __attribute__((ext_vector_type(4)));
typedef unsigned int u32x2 __attribute__((ext_vector_type(2)));

__device__ __forceinline__ f32x4 mfma32(f16x8 a, f16x8 b, f32x4 c) {
  return __builtin_amdgcn_mfma_f32_16x16x32_f16(a, b, c, 0, 0, 0);
}
__device__ __forceinline__ f32x4 mfma16(f16x4 a, f16x4 b, f32x4 c) {
#if __has_builtin(__builtin_amdgcn_mfma_f32_16x16x16f16)
  return __builtin_amdgcn_mfma_f32_16x16x16f16(a, b, c, 0, 0, 0);
#else
  f32x4 d;
  asm volatile("v_mfma_f32_16x16x16_f16 %0, %1, %2, %3"
               : "=v"(d) : "v"(a), "v"(b), "v"(c));
  return d;
#endif
}

__device__ __forceinline__ unsigned pk2(float a, float b) {
  union { fp16x2 h; unsigned u; } cv;
  cv.h = __builtin_amdgcn_cvt_pkrtz(a, b);
  return cv.u;
}

// hardware transpose read: per-lane vaddr (32-bit LDS byte offset) = base + 8*lane;
// delivers, for lane l, elems j=0..3 = lds_elem[(l&15) + 16*j + 64*(l>>4)] rel. to base
#define TR_READ(dst, addr, OFF) \
  asm volatile("ds_read_b64_tr_b16 %0, %1 offset:" OFF \
               : "=v"(dst) : "v"(addr) : "memory")

// ---- pre-convert weights to fp16 in workspace (L2-resident reuse) ----
__global__ void cvt_weights(const float* __restrict__ qw, const float* __restrict__ cw,
                            _Float16* __restrict__ wq, _Float16* __restrict__ wc) {
  const int i = blockIdx.x * 256 + threadIdx.x;
  if (i < 384 * 128) wq[i] = (_Float16)qw[i];
  if (i < 128 * 128) wc[i] = (_Float16)cw[i];
}

// One 4x4x4 window per block. 4 waves; wave wv owns heads {2wv, 2wv+1}.
// R9 lesson: the pipeline's live state (~150 regs) exceeded every budget —
// registers must be SHED, not re-budgeted. This version:
//  * QKV GEMM processes ONE column-block (q|k|v) at a time: acc[4] (16 regs)
//    not acc[4][3] (48); each result goes straight to LDS.
//  * v lives in LDS ([c][s], XOR-swizzled) — no vp regs, no PV shuffles;
//    PV A-operand = one ds_read_b128 per kc.
//  * peak live ~100 regs -> fits __launch_bounds__(256,4)'s 128 cap.
// LDS (40KB, 4 blocks/CU exactly):
//   xsm [16KB]: x-window / o buffer [64 t][128 ch], byte = t*256 + (2ch ^ ((t&15)<<4))
//   wsm[wv] (6KB/wave): [0,2048) k  as [si][16ch][16tok] (tr-read layout)
//                       [2048,4096) q same;   P chunk [64t][32s] overwrites [0,4096)
//                       [4096,6144) v as [c][s]: byte = c*128 + (2s ^ ((c&7)<<4))
__global__ void __launch_bounds__(256, 4)
win_attn(const float* __restrict__ xg, const _Float16* __restrict__ wq,
         const float* __restrict__ qbias, const _Float16* __restrict__ wc,
         const float* __restrict__ cb, float* __restrict__ outg)
{
  __shared__ char xsm[16384];
  __shared__ char wsm[4][6144];

  const int tid  = threadIdx.x;
  const int lane = tid & 63;
  const int wv   = tid >> 6;
  const int l15  = lane & 15;
  const int g    = lane >> 4;

  // XCD-bijective swizzle (4096 % 8 == 0): contiguous ww-ranges per XCD
  const int raw = blockIdx.x;
  const int wid = ((raw & 7) << 9) | (raw >> 3);
  const int ww = wid & 15, hh = (wid >> 4) & 15, dd = (wid >> 8) & 7, bb = wid >> 11;

  const f32x4 fz = {0.f, 0.f, 0.f, 0.f};

  // ---------------- stage x window -> xsm (fp16, swizzled token-major) ----------------
  {
    const int m4 = lane & 3, q4 = lane >> 2;
    const int i0 = q4 >> 2, i1 = q4 & 3;
    const int z = dd * 4 + i0, y = hh * 4 + i1;
    const bool yv   = (y < 62);
    const bool full = (ww < 15);
    float va[8][4];
#pragma unroll
    for (int it = 0; it < 8; ++it) {           // issue all global loads first
      const int c = wv * 32 + it * 4 + m4;
      const float* src = xg + (((size_t)(bb * 128 + c) * 32 + (size_t)z) * 3844
                               + (size_t)(y * 62 + ww * 4));
      float a0 = 0.f, a1 = 0.f, a2 = 0.f, a3 = 0.f;
      if (yv) {
        const float2 lo = *reinterpret_cast<const float2*>(src);
        a0 = lo.x; a1 = lo.y;
        if (full) {
          const float2 hi = *reinterpret_cast<const float2*>(src + 2);
          a2 = hi.x; a3 = hi.y;
        }
      }
      va[it][0] = a0; va[it][1] = a1; va[it][2] = a2; va[it][3] = a3;
    }
#pragma unroll
    for (int it = 0; it < 8; ++it) {           // 4x4 lane-quad transpose, packed b64 write
      float v0 = va[it][0], v1 = va[it][1], v2 = va[it][2], v3 = va[it][3];
      float t0 = __shfl_xor((m4 & 1) ? v0 : v1, 1);
      float t1 = __shfl_xor((m4 & 1) ? v2 : v3, 1);
      if (m4 & 1) { v0 = t0; v2 = t1; } else { v1 = t0; v3 = t1; }
      float t2 = __shfl_xor((m4 & 2) ? v0 : v2, 2);
      float t3 = __shfl_xor((m4 & 2) ? v1 : v3, 2);
      if (m4 & 2) { v0 = t2; v1 = t3; } else { v2 = t2; v3 = t3; }
      f16x4 pk; pk[0] = (_Float16)v0; pk[1] = (_Float16)v1;
                pk[2] = (_Float16)v2; pk[3] = (_Float16)v3;
      const int c0 = wv * 32 + it * 4;         // lane holds xs[t=lane][c0..c0+3]
      *reinterpret_cast<f16x4*>(xsm + ((lane * 256 + 2 * c0) ^ ((lane & 15) << 4))) = pk;
    }
  }
  __syncthreads();

  // ---------------- per-head pipeline: QKV GEMM -> attention ----------------
  char* sb = wsm[wv];
  const unsigned sb32 = (unsigned)(unsigned long long)sb;   // LDS byte offset
  const unsigned trb  = sb32 + 8u * (unsigned)lane;
  const int vswz = (l15 & 7) << 4;

  unsigned long long pm = 0ull;                     // pad flag per token
  if (hh == 15) pm |= 0xFF00FF00FF00FF00ull;        // i1 >= 2
  if (ww == 15) pm |= 0xCCCCCCCCCCCCCCCCull;        // i2 >= 2

  const float LOG2E = 1.4426950408889634f;
  const int swzA = l15 << 4;

  unsigned opk0[4][2], opk1[4][2];                  // packed o per head

#pragma unroll
  for (int hp = 0; hp < 2; ++hp) {
    __builtin_amdgcn_sched_barrier(0);              // keep the two heads' code apart
    // ---- QKV GEMM, one 16-col block at a time: co 0=q, 1=k, 2=v ----
#pragma unroll
    for (int co = 0; co < 3; ++co) {
      f32x4 acc[4] = {fz, fz, fz, fz};
      const int col = co * 128 + wv * 32 + hp * 16 + l15;
#pragma unroll
      for (int kk = 0; kk < 4; ++kk) {
        const f16x8 bfr = *reinterpret_cast<const f16x8*>(wq + col * 128 + kk * 32 + g * 8);
#pragma unroll
        for (int ri = 0; ri < 4; ++ri) {
          const f16x8 a = *reinterpret_cast<const f16x8*>(
              xsm + (ri * 16 + l15) * 256 + ((kk * 64 + g * 16) ^ swzA));
          acc[ri] = mfma32(a, bfr, acc[ri]);
        }
      }
      const float bias = qbias[col];
      const float sc = (co == 0) ? 0.25f : 1.0f;   // fold softmax scale into q
#pragma unroll
      for (int ri = 0; ri < 4; ++ri)
#pragma unroll
        for (int r = 0; r < 4; ++r) acc[ri][r] = (acc[ri][r] + bias) * sc;

      if (co == 2) {
        // v -> [c][s]: lane holds v[t = ri*16+g*4+r][c = l15]
#pragma unroll
        for (int ri = 0; ri < 4; ++ri) {
          const int s0 = ri * 16 + g * 4;
          *reinterpret_cast<unsigned*>(sb + 4096 + l15 * 128 + ((2 * s0) ^ vswz))
              = pk2(acc[ri][0], acc[ri][1]);
          *reinterpret_cast<unsigned*>(sb + 4096 + l15 * 128 + ((2 * (s0 + 2)) ^ vswz))
              = pk2(acc[ri][2], acc[ri][3]);
        }
      } else {
        // q/k -> tr-read layout: element off = si*256 + ch*16 + (tok&15)
        const int base = (co == 0) ? 2048 : 0;
#pragma unroll
        for (int ri = 0; ri < 4; ++ri) {
          const int off = ri * 512 + l15 * 32 + g * 8;  // bytes
          u32x2 w;
          w[0] = pk2(acc[ri][0], acc[ri][1]);
          w[1] = pk2(acc[ri][2], acc[ri][3]);
          *reinterpret_cast<u32x2*>(sb + base + off) = w;
        }
      }
      __builtin_amdgcn_sched_barrier(0);            // keep co phases apart (16-acc peak)
    }
    asm volatile("s_waitcnt lgkmcnt(0)" ::: "memory");

    // ---- tr reads: ka[si] = k[s=si*16+l15][ch=g*4+j], qa[tj] = q[t=tj*16+l15][ch=g*4+j]
    f16x4 ka[4], qa[4];
    TR_READ(ka[0], trb, "0");
    TR_READ(ka[1], trb, "512");
    TR_READ(ka[2], trb, "1024");
    TR_READ(ka[3], trb, "1536");
    TR_READ(qa[0], trb, "2048");
    TR_READ(qa[1], trb, "2560");
    TR_READ(qa[2], trb, "3072");
    TR_READ(qa[3], trb, "3584");
    asm volatile("s_waitcnt lgkmcnt(0)" ::: "memory");
    __builtin_amdgcn_sched_barrier(0);

    // ---- S^T tiles: st[si][tj] -> s = si*16+g*4+r, t = tj*16+l15 ----
    f32x4 st[4][4];
#pragma unroll
    for (int si = 0; si < 4; ++si)
#pragma unroll
      for (int tj = 0; tj < 4; ++tj) st[si][tj] = mfma16(ka[si], qa[tj], fz);

    // pad mask: -1000 where pad(s) != pad(t)
    if (pm) {
#pragma unroll
      for (int tj = 0; tj < 4; ++tj) {
        const int t = tj * 16 + l15;
        const unsigned ft = (unsigned)(pm >> t) & 1u;
#pragma unroll
        for (int si = 0; si < 4; ++si)
#pragma unroll
          for (int r = 0; r < 4; ++r) {
            const int s = si * 16 + g * 4 + r;
            const unsigned fs = (unsigned)(pm >> s) & 1u;
            if (fs != ft) st[si][tj][r] -= 1000.f;
          }
      }
    }

    // softmax over s: 16 lane-local values per tj + 2 shfl (g groups)
#pragma unroll
    for (int tj = 0; tj < 4; ++tj) {
      float mx = st[0][tj][0];
#pragma unroll
      for (int si = 0; si < 4; ++si)
#pragma unroll
        for (int r = 0; r < 4; ++r) mx = fmaxf(mx, st[si][tj][r]);
      mx = fmaxf(mx, __shfl_xor(mx, 16));
      mx = fmaxf(mx, __shfl_xor(mx, 32));
      float sum = 0.f;
#pragma unroll
      for (int si = 0; si < 4; ++si)
#pragma unroll
        for (int r = 0; r < 4; ++r) {
          const float e = __builtin_amdgcn_exp2f((st[si][tj][r] - mx) * LOG2E);
          st[si][tj][r] = e; sum += e;
        }
      sum += __shfl_xor(sum, 16);
      sum += __shfl_xor(sum, 32);
      const float inv = __builtin_amdgcn_rcpf(sum);
#pragma unroll
      for (int si = 0; si < 4; ++si)
#pragma unroll
        for (int r = 0; r < 4; ++r) st[si][tj][r] *= inv;
    }

    // ---- PV as o^T = v^T @ P^T, chunked over s (kc = 0,1) ----
    f32x4 oat[4] = {fz, fz, fz, fz};
#pragma unroll
    for (int kc = 0; kc < 2; ++kc) {
      // write P chunk [64 t][32 s]: s_local = (ri&1)*16 + g*4 + r
#pragma unroll
      for (int half = 0; half < 2; ++half) {
        const int ri = 2 * kc + half;
#pragma unroll
        for (int tj = 0; tj < 4; ++tj) {
          const int t = tj * 16 + l15;
          u32x2 w;
          w[0] = pk2(st[ri][tj][0], st[ri][tj][1]);
          w[1] = pk2(st[ri][tj][2], st[ri][tj][3]);
          *reinterpret_cast<u32x2*>(sb + t * 64 + ((half * 32 + g * 8) ^ ((t & 3) << 4))) = w;
        }
      }
      asm volatile("s_waitcnt lgkmcnt(0)" ::: "memory");
      // av = v[s = kc*32 + g*8 + j][c = l15]: one b128 from the v region
      const f16x8 av = *reinterpret_cast<const f16x8*>(
          sb + 4096 + l15 * 128 + ((kc * 64 + g * 16) ^ vswz));
      // pa[tj] = P[t = tj*16 + l15][s_local = g*8 + e]; mfma(av, pa) -> D[c][t]
#pragma unroll
      for (int tj = 0; tj < 4; ++tj) {
        const int t = tj * 16 + l15;
        const f16x8 pa = *reinterpret_cast<const f16x8*>(
            sb + t * 64 + ((g * 16) ^ ((t & 3) << 4)));
        oat[tj] = mfma32(av, pa, oat[tj]);
      }
    }

    // pack o: lane holds o[t = tj*16+l15][c = h*16 + g*4 + {0..3}]
    if (hp == 0) {
#pragma unroll
      for (int tj = 0; tj < 4; ++tj) {
        opk0[tj][0] = pk2(oat[tj][0], oat[tj][1]);
        opk0[tj][1] = pk2(oat[tj][2], oat[tj][3]);
      }
    } else {
#pragma unroll
      for (int tj = 0; tj < 4; ++tj) {
        opk1[tj][0] = pk2(oat[tj][0], oat[tj][1]);
        opk1[tj][1] = pk2(oat[tj][2], oat[tj][3]);
      }
    }
  }
  __syncthreads();   // all waves done reading x from xsm -> becomes o buffer

  // ---- write o (both heads) to xsm ----
#pragma unroll
  for (int tj = 0; tj < 4; ++tj) {
    const int t = tj * 16 + l15;
    u32x2 w0; w0[0] = opk0[tj][0]; w0[1] = opk0[tj][1];
    *reinterpret_cast<u32x2*>(xsm + t * 256 + (((2 * wv) * 32 + g * 8) ^ ((t & 15) << 4))) = w0;
    u32x2 w1; w1[0] = opk1[tj][0]; w1[1] = opk1[tj][1];
    *reinterpret_cast<u32x2*>(xsm + t * 256 + (((2 * wv + 1) * 32 + g * 8) ^ ((t & 15) << 4))) = w1;
  }
  __syncthreads();

  // ---------------- 1x1x1 conv GEMM + store ----------------
  f32x4 cacc[4][2];
#pragma unroll
  for (int i = 0; i < 4; ++i) { cacc[i][0] = fz; cacc[i][1] = fz; }
#pragma unroll
  for (int kk = 0; kk < 4; ++kk) {
    f16x8 a[4];
#pragma unroll
    for (int ri = 0; ri < 4; ++ri)
      a[ri] = *reinterpret_cast<const f16x8*>(
          xsm + (ri * 16 + l15) * 256 + ((kk * 64 + g * 16) ^ swzA));
#pragma unroll
    for (int co = 0; co < 2; ++co) {
      const int cout = wv * 32 + co * 16 + l15;
      const f16x8 bfr = *reinterpret_cast<const f16x8*>(wc + cout * 128 + kk * 32 + g * 8);
#pragma unroll
      for (int ri = 0; ri < 4; ++ri) cacc[ri][co] = mfma32(a[ri], bfr, cacc[ri][co]);
    }
  }
  // rows: t = ri*16 + g*4 + r -> i0 = ri (z), i1 = g (y), i2 = r (x)
  const int y = hh * 4 + g;
  if (y < 62) {
#pragma unroll
    for (int co = 0; co < 2; ++co) {
      const int cout = wv * 32 + co * 16 + l15;
      const float bias = cb[cout];
#pragma unroll
      for (int ri = 0; ri < 4; ++ri) {
        const int z = dd * 4 + ri;
        float* dst = outg + (((size_t)(bb * 128 + cout) * 32 + (size_t)z) * 3844
                             + (size_t)(y * 62 + ww * 4));
        float2 lo; lo.x = cacc[ri][co][0] + bias; lo.y = cacc[ri][co][1] + bias;
        *reinterpret_cast<float2*>(dst) = lo;
        if (ww < 15) {
          float2 hi; hi.x = cacc[ri][co][2] + bias; hi.y = cacc[ri][co][3] + bias;
          *reinterpret_cast<float2*>(dst + 2) = hi;
        }
      }
    }
  }
}

extern "C" void kernel_launch(void* const* d_in, const int* in_sizes, int n_in,
                              void* d_out, int out_size, void* d_ws, size_t ws_size,
                              hipStream_t stream) {
  const float* x  = (const float*)d_in[0];
  const float* qw = (const float*)d_in[1];
  const float* qb = (const float*)d_in[2];
  const float* cw = (const float*)d_in[3];
  const float* cb = (const float*)d_in[4];
  float* out = (float*)d_out;

  if (ws_size < (size_t)(384 * 128 + 128 * 128) * sizeof(_Float16)) return;
  _Float16* wq = (_Float16*)d_ws;
  _Float16* wc = wq + 384 * 128;

  cvt_weights<<<192, 256, 0, stream>>>(qw, cw, wq, wc);
  win_attn<<<4096, 256, 0, stream>>>(x, wq, qb, wc, cb, out);
}

// Round 11
// 165.239 us; speedup vs baseline: 1.5464x; 1.1506x over previous
//
#include <hip/hip_runtime.h>

typedef _Float16 f16x8 __attribute__((ext_vector_type(8)));
typedef _Float16 f16x4 __attribute__((ext_vector_type(4)));
typedef __fp16   fp16x2 __attribute__((ext_vector_type(2)));
typedef float    f32x4 __attribute__((ext_vector_type(4)));
typedef unsigned int u32x2 __attribute__((ext_vector_type(2)));

__device__ __forceinline__ f32x4 mfma32(f16x8 a, f16x8 b, f32x4 c) {
  return __builtin_amdgcn_mfma_f32_16x16x32_f16(a, b, c, 0, 0, 0);
}
__device__ __forceinline__ f32x4 mfma16(f16x4 a, f16x4 b, f32x4 c) {
#if __has_builtin(__builtin_amdgcn_mfma_f32_16x16x16f16)
  return __builtin_amdgcn_mfma_f32_16x16x16f16(a, b, c, 0, 0, 0);
#else
  f32x4 d;
  asm volatile("v_mfma_f32_16x16x16_f16 %0, %1, %2, %3"
               : "=v"(d) : "v"(a), "v"(b), "v"(c));
  return d;
#endif
}

__device__ __forceinline__ unsigned pk2(float a, float b) {
  union { fp16x2 h; unsigned u; } cv;
  cv.h = __builtin_amdgcn_cvt_pkrtz(a, b);
  return cv.u;
}

// hardware transpose read: per-lane vaddr (32-bit LDS byte offset) = base + 8*lane;
// delivers, for lane l, elems j=0..3 = lds_elem[(l&15) + 16*j + 64*(l>>4)] rel. to base
#define TR_READ(dst, addr, OFF) \
  asm volatile("ds_read_b64_tr_b16 %0, %1 offset:" OFF \
               : "=v"(dst) : "v"(addr) : "memory")

// ---- pre-convert weights to fp16 in workspace (L2-resident reuse) ----
__global__ void cvt_weights(const float* __restrict__ qw, const float* __restrict__ cw,
                            _Float16* __restrict__ wq, _Float16* __restrict__ wc) {
  const int i = blockIdx.x * 256 + threadIdx.x;
  if (i < 384 * 128) wq[i] = (_Float16)qw[i];
  if (i < 128 * 128) wc[i] = (_Float16)cw[i];
}

// One 4x4x4 window per block. 4 waves; wave wv owns heads {2wv, 2wv+1}.
// Register-budget lessons: R6/R7 rolled loops -> scratch; R9 acc[4][3]+st[4][4]
// -> ~150 live regs, spills any budget; R10 shed acc (one co at a time, v in
// LDS) -> st[4][4]=64 regs remained the hog. R11: softmax/PV processed in TWO
// tj-pair chunks (st2[4][2]=32 regs); P chunk [32t][64s]=4KB reuses the dead
// q/k region; av0/av1 hoisted. Peak live ~95 regs -> fits (256,4)'s 128 cap.
// LDS (40KB, 4 blocks/CU):
//   xsm [16KB]: x-window / o buffer [64 t][128 ch], byte = t*256 + (2ch ^ ((t&15)<<4))
//   wsm[wv] (6KB/wave): [0,2048) k as [si][16ch][16tok] (tr-read layout),
//                       [2048,4096) q same; P chunk [32t][64s] overwrites [0,4096):
//                         byte = t_local*128 + (2s ^ ((l15&7)<<4))
//                       [4096,6144) v as [c][s]: byte = c*128 + (2s ^ ((c&7)<<4))
__global__ void __launch_bounds__(256, 4)
win_attn(const float* __restrict__ xg, const _Float16* __restrict__ wq,
         const float* __restrict__ qbias, const _Float16* __restrict__ wc,
         const float* __restrict__ cb, float* __restrict__ outg)
{
  __shared__ char xsm[16384];
  __shared__ char wsm[4][6144];

  const int tid  = threadIdx.x;
  const int lane = tid & 63;
  const int wv   = tid >> 6;
  const int l15  = lane & 15;
  const int g    = lane >> 4;

  // XCD-bijective swizzle (4096 % 8 == 0): contiguous ww-ranges per XCD
  const int raw = blockIdx.x;
  const int wid = ((raw & 7) << 9) | (raw >> 3);
  const int ww = wid & 15, hh = (wid >> 4) & 15, dd = (wid >> 8) & 7, bb = wid >> 11;

  const f32x4 fz = {0.f, 0.f, 0.f, 0.f};

  // ---------------- stage x window -> xsm (fp16, swizzled token-major) ----------------
  {
    const int m4 = lane & 3, q4 = lane >> 2;
    const int i0 = q4 >> 2, i1 = q4 & 3;
    const int z = dd * 4 + i0, y = hh * 4 + i1;
    const bool yv   = (y < 62);
    const bool full = (ww < 15);
    float va[8][4];
#pragma unroll
    for (int it = 0; it < 8; ++it) {           // issue all global loads first
      const int c = wv * 32 + it * 4 + m4;
      const float* src = xg + (((size_t)(bb * 128 + c) * 32 + (size_t)z) * 3844
                               + (size_t)(y * 62 + ww * 4));
      float a0 = 0.f, a1 = 0.f, a2 = 0.f, a3 = 0.f;
      if (yv) {
        const float2 lo = *reinterpret_cast<const float2*>(src);
        a0 = lo.x; a1 = lo.y;
        if (full) {
          const float2 hi = *reinterpret_cast<const float2*>(src + 2);
          a2 = hi.x; a3 = hi.y;
        }
      }
      va[it][0] = a0; va[it][1] = a1; va[it][2] = a2; va[it][3] = a3;
    }
#pragma unroll
    for (int it = 0; it < 8; ++it) {           // 4x4 lane-quad transpose, packed b64 write
      float v0 = va[it][0], v1 = va[it][1], v2 = va[it][2], v3 = va[it][3];
      float t0 = __shfl_xor((m4 & 1) ? v0 : v1, 1);
      float t1 = __shfl_xor((m4 & 1) ? v2 : v3, 1);
      if (m4 & 1) { v0 = t0; v2 = t1; } else { v1 = t0; v3 = t1; }
      float t2 = __shfl_xor((m4 & 2) ? v0 : v2, 2);
      float t3 = __shfl_xor((m4 & 2) ? v1 : v3, 2);
      if (m4 & 2) { v0 = t2; v1 = t3; } else { v2 = t2; v3 = t3; }
      f16x4 pk; pk[0] = (_Float16)v0; pk[1] = (_Float16)v1;
                pk[2] = (_Float16)v2; pk[3] = (_Float16)v3;
      const int c0 = wv * 32 + it * 4;         // lane holds xs[t=lane][c0..c0+3]
      *reinterpret_cast<f16x4*>(xsm + ((lane * 256 + 2 * c0) ^ ((lane & 15) << 4))) = pk;
    }
  }
  __syncthreads();

  // ---------------- per-head pipeline: QKV GEMM -> attention ----------------
  char* sb = wsm[wv];
  const unsigned sb32 = (unsigned)(unsigned long long)sb;   // LDS byte offset
  const unsigned trb  = sb32 + 8u * (unsigned)lane;
  const int vswz = (l15 & 7) << 4;              // also the P-chunk swizzle (t&7 == l15&7)

  unsigned long long pm = 0ull;                     // pad flag per token
  if (hh == 15) pm |= 0xFF00FF00FF00FF00ull;        // i1 >= 2
  if (ww == 15) pm |= 0xCCCCCCCCCCCCCCCCull;        // i2 >= 2

  const float LOG2E = 1.4426950408889634f;
  const int swzA = l15 << 4;

  unsigned opk0[4][2], opk1[4][2];                  // packed o per head

#pragma unroll
  for (int hp = 0; hp < 2; ++hp) {
    __builtin_amdgcn_sched_barrier(0);              // keep the two heads' code apart
    // ---- QKV GEMM, one 16-col block at a time: co 0=q, 1=k, 2=v ----
#pragma unroll
    for (int co = 0; co < 3; ++co) {
      f32x4 acc[4] = {fz, fz, fz, fz};
      const int col = co * 128 + wv * 32 + hp * 16 + l15;
#pragma unroll
      for (int kk = 0; kk < 4; ++kk) {
        const f16x8 bfr = *reinterpret_cast<const f16x8*>(wq + col * 128 + kk * 32 + g * 8);
#pragma unroll
        for (int ri = 0; ri < 4; ++ri) {
          const f16x8 a = *reinterpret_cast<const f16x8*>(
              xsm + (ri * 16 + l15) * 256 + ((kk * 64 + g * 16) ^ swzA));
          acc[ri] = mfma32(a, bfr, acc[ri]);
        }
      }
      const float bias = qbias[col];
      const float sc = (co == 0) ? 0.25f : 1.0f;   // fold softmax scale into q
#pragma unroll
      for (int ri = 0; ri < 4; ++ri)
#pragma unroll
        for (int r = 0; r < 4; ++r) acc[ri][r] = (acc[ri][r] + bias) * sc;

      if (co == 2) {
        // v -> [c][s]: lane holds v[t = ri*16+g*4+r][c = l15]
#pragma unroll
        for (int ri = 0; ri < 4; ++ri) {
          const int s0 = ri * 16 + g * 4;
          *reinterpret_cast<unsigned*>(sb + 4096 + l15 * 128 + ((2 * s0) ^ vswz))
              = pk2(acc[ri][0], acc[ri][1]);
          *reinterpret_cast<unsigned*>(sb + 4096 + l15 * 128 + ((2 * (s0 + 2)) ^ vswz))
              = pk2(acc[ri][2], acc[ri][3]);
        }
      } else {
        // q/k -> tr-read layout: element off = si*256 + ch*16 + (tok&15)
        const int base = (co == 0) ? 2048 : 0;
#pragma unroll
        for (int ri = 0; ri < 4; ++ri) {
          const int off = ri * 512 + l15 * 32 + g * 8;  // bytes
          u32x2 w;
          w[0] = pk2(acc[ri][0], acc[ri][1]);
          w[1] = pk2(acc[ri][2], acc[ri][3]);
          *reinterpret_cast<u32x2*>(sb + base + off) = w;
        }
      }
      __builtin_amdgcn_sched_barrier(0);            // keep co phases apart (16-acc peak)
    }
    asm volatile("s_waitcnt lgkmcnt(0)" ::: "memory");

    // ---- tr reads: ka[si] = k[s=si*16+l15][ch=g*4+j], qa[tj] = q[t=tj*16+l15][ch=g*4+j]
    f16x4 ka[4], qa[4];
    TR_READ(ka[0], trb, "0");
    TR_READ(ka[1], trb, "512");
    TR_READ(ka[2], trb, "1024");
    TR_READ(ka[3], trb, "1536");
    TR_READ(qa[0], trb, "2048");
    TR_READ(qa[1], trb, "2560");
    TR_READ(qa[2], trb, "3072");
    TR_READ(qa[3], trb, "3584");
    // v fragments (read once, reused by both tj-pairs)
    f16x8 av0, av1;
    av0 = *reinterpret_cast<const f16x8*>(sb + 4096 + l15 * 128 + ((g * 16) ^ vswz));
    av1 = *reinterpret_cast<const f16x8*>(sb + 4096 + l15 * 128 + ((64 + g * 16) ^ vswz));
    asm volatile("s_waitcnt lgkmcnt(0)" ::: "memory");
    __builtin_amdgcn_sched_barrier(0);

    f32x4 oa0, oa1;
    // ---- two tj-pair chunks: S^T -> softmax -> P chunk -> PV ----
#pragma unroll
    for (int tjp = 0; tjp < 2; ++tjp) {
      const int tj0 = 2 * tjp, tj1 = 2 * tjp + 1;
      // st2[si][tjc]: s = si*16+g*4+r, t = (tjp*2+tjc)*16 + l15
      f32x4 st2[4][2];
#pragma unroll
      for (int si = 0; si < 4; ++si) {
        st2[si][0] = mfma16(ka[si], qa[tj0], fz);
        st2[si][1] = mfma16(ka[si], qa[tj1], fz);
      }

      // pad mask: -1000 where pad(s) != pad(t)
      if (pm) {
#pragma unroll
        for (int tjc = 0; tjc < 2; ++tjc) {
          const int t = (2 * tjp + tjc) * 16 + l15;
          const unsigned ft = (unsigned)(pm >> t) & 1u;
#pragma unroll
          for (int si = 0; si < 4; ++si)
#pragma unroll
            for (int r = 0; r < 4; ++r) {
              const int s = si * 16 + g * 4 + r;
              const unsigned fs = (unsigned)(pm >> s) & 1u;
              if (fs != ft) st2[si][tjc][r] -= 1000.f;
            }
        }
      }

      // softmax over s (16 lane-local + 2 shfl), per tjc
#pragma unroll
      for (int tjc = 0; tjc < 2; ++tjc) {
        float mx = st2[0][tjc][0];
#pragma unroll
        for (int si = 0; si < 4; ++si)
#pragma unroll
          for (int r = 0; r < 4; ++r) mx = fmaxf(mx, st2[si][tjc][r]);
        mx = fmaxf(mx, __shfl_xor(mx, 16));
        mx = fmaxf(mx, __shfl_xor(mx, 32));
        float sum = 0.f;
#pragma unroll
        for (int si = 0; si < 4; ++si)
#pragma unroll
          for (int r = 0; r < 4; ++r) {
            const float e = __builtin_amdgcn_exp2f((st2[si][tjc][r] - mx) * LOG2E);
            st2[si][tjc][r] = e; sum += e;
          }
        sum += __shfl_xor(sum, 16);
        sum += __shfl_xor(sum, 32);
        const float inv = __builtin_amdgcn_rcpf(sum);
#pragma unroll
        for (int si = 0; si < 4; ++si)
#pragma unroll
          for (int r = 0; r < 4; ++r) st2[si][tjc][r] *= inv;
      }

      // write P chunk [32 t_local][64 s]: byte = t_local*128 + (2s ^ vswz)
#pragma unroll
      for (int tjc = 0; tjc < 2; ++tjc) {
        const int tl = tjc * 16 + l15;
#pragma unroll
        for (int si = 0; si < 4; ++si) {
          u32x2 w;
          w[0] = pk2(st2[si][tjc][0], st2[si][tjc][1]);
          w[1] = pk2(st2[si][tjc][2], st2[si][tjc][3]);
          *reinterpret_cast<u32x2*>(sb + tl * 128 + ((si * 32 + g * 8) ^ vswz)) = w;
        }
      }
      asm volatile("s_waitcnt lgkmcnt(0)" ::: "memory");

      // PV: oa[tjc] += av[kc] x P^T fragment
      oa0 = fz; oa1 = fz;
      {
        const f16x8 pa00 = *reinterpret_cast<const f16x8*>(
            sb + l15 * 128 + ((g * 16) ^ vswz));
        const f16x8 pa10 = *reinterpret_cast<const f16x8*>(
            sb + (16 + l15) * 128 + ((g * 16) ^ vswz));
        oa0 = mfma32(av0, pa00, oa0);
        oa1 = mfma32(av0, pa10, oa1);
        const f16x8 pa01 = *reinterpret_cast<const f16x8*>(
            sb + l15 * 128 + ((64 + g * 16) ^ vswz));
        const f16x8 pa11 = *reinterpret_cast<const f16x8*>(
            sb + (16 + l15) * 128 + ((64 + g * 16) ^ vswz));
        oa0 = mfma32(av1, pa01, oa0);
        oa1 = mfma32(av1, pa11, oa1);
      }

      // pack o: lane holds o[t][c = h*16 + g*4 + r]
      if (hp == 0) {
        opk0[tj0][0] = pk2(oa0[0], oa0[1]); opk0[tj0][1] = pk2(oa0[2], oa0[3]);
        opk0[tj1][0] = pk2(oa1[0], oa1[1]); opk0[tj1][1] = pk2(oa1[2], oa1[3]);
      } else {
        opk1[tj0][0] = pk2(oa0[0], oa0[1]); opk1[tj0][1] = pk2(oa0[2], oa0[3]);
        opk1[tj1][0] = pk2(oa1[0], oa1[1]); opk1[tj1][1] = pk2(oa1[2], oa1[3]);
      }
      __builtin_amdgcn_sched_barrier(0);            // keep tj-pairs apart (st2 peak)
    }
  }
  __syncthreads();   // all waves done reading x from xsm -> becomes o buffer

  // ---- write o (both heads) to xsm ----
#pragma unroll
  for (int tj = 0; tj < 4; ++tj) {
    const int t = tj * 16 + l15;
    u32x2 w0; w0[0] = opk0[tj][0]; w0[1] = opk0[tj][1];
    *reinterpret_cast<u32x2*>(xsm + t * 256 + (((2 * wv) * 32 + g * 8) ^ ((t & 15) << 4))) = w0;
    u32x2 w1; w1[0] = opk1[tj][0]; w1[1] = opk1[tj][1];
    *reinterpret_cast<u32x2*>(xsm + t * 256 + (((2 * wv + 1) * 32 + g * 8) ^ ((t & 15) << 4))) = w1;
  }
  __syncthreads();

  // ---------------- 1x1x1 conv GEMM + store ----------------
  f32x4 cacc[4][2];
#pragma unroll
  for (int i = 0; i < 4; ++i) { cacc[i][0] = fz; cacc[i][1] = fz; }
#pragma unroll
  for (int kk = 0; kk < 4; ++kk) {
    f16x8 a[4];
#pragma unroll
    for (int ri = 0; ri < 4; ++ri)
      a[ri] = *reinterpret_cast<const f16x8*>(
          xsm + (ri * 16 + l15) * 256 + ((kk * 64 + g * 16) ^ swzA));
#pragma unroll
    for (int co = 0; co < 2; ++co) {
      const int cout = wv * 32 + co * 16 + l15;
      const f16x8 bfr = *reinterpret_cast<const f16x8*>(wc + cout * 128 + kk * 32 + g * 8);
#pragma unroll
      for (int ri = 0; ri < 4; ++ri) cacc[ri][co] = mfma32(a[ri], bfr, cacc[ri][co]);
    }
  }
  // rows: t = ri*16 + g*4 + r -> i0 = ri (z), i1 = g (y), i2 = r (x)
  const int y = hh * 4 + g;
  if (y < 62) {
#pragma unroll
    for (int co = 0; co < 2; ++co) {
      const int cout = wv * 32 + co * 16 + l15;
      const float bias = cb[cout];
#pragma unroll
      for (int ri = 0; ri < 4; ++ri) {
        const int z = dd * 4 + ri;
        float* dst = outg + (((size_t)(bb * 128 + cout) * 32 + (size_t)z) * 3844
                             + (size_t)(y * 62 + ww * 4));
        float2 lo; lo.x = cacc[ri][co][0] + bias; lo.y = cacc[ri][co][1] + bias;
        *reinterpret_cast<float2*>(dst) = lo;
        if (ww < 15) {
          float2 hi; hi.x = cacc[ri][co][2] + bias; hi.y = cacc[ri][co][3] + bias;
          *reinterpret_cast<float2*>(dst + 2) = hi;
        }
      }
    }
  }
}

extern "C" void kernel_launch(void* const* d_in, const int* in_sizes, int n_in,
                              void* d_out, int out_size, void* d_ws, size_t ws_size,
                              hipStream_t stream) {
  const float* x  = (const float*)d_in[0];
  const float* qw = (const float*)d_in[1];
  const float* qb = (const float*)d_in[2];
  const float* cw = (const float*)d_in[3];
  const float* cb = (const float*)d_in[4];
  float* out = (float*)d_out;

  if (ws_size < (size_t)(384 * 128 + 128 * 128) * sizeof(_Float16)) return;
  _Float16* wq = (_Float16*)d_ws;
  _Float16* wc = wq + 384 * 128;

  cvt_weights<<<192, 256, 0, stream>>>(qw, cw, wq, wc);
  win_attn<<<4096, 256, 0, stream>>>(x, wq, qb, wc, cb, out);
}